// Round 3
// baseline (957.606 us; speedup 1.0000x reference)
//
#include <hip/hip_runtime.h>
#include <hip/hip_bf16.h>
#include <hip/hip_cooperative_groups.h>

namespace cg = cooperative_groups;

// AgreementRouting, single cooperative kernel. B=128, IC=1152, OC=10, D=16.
//
// Grid: 1024 blocks x 256 threads (4 blocks/CU co-resident). Each block owns
// 9 (b,ich) units, all with the SAME b (9|72); 8 blocks per b (part = bid%8).
// Phases P0..P3 separated by grid.sync(); per-phase s reduction is
// block-local (LDS) -> one device-scope partial store per block; readers sum
// the 8 partials with device-scope loads (cross-XCD coherent, deterministic).
//
// Lane scheme per 16-lane group (one (b,i) slice = 10x16 f32):
//   l=tid&15, h=l>>3. Lane owns (j=2k+h, d=2(l&7)..2(l&7)+1), k=0..4
//   == linear float offset 32k+2l (contiguous 128B per group).

#define B_    128
#define IC_   1152
#define OC_   10
#define ROW_  160
#define WPS_  80          // bf16 dwords per slice
#define ICH_  16
#define NBI_  72
#define SOUT_ 20480
#define NBLK_ 1024
#define UPB_  9
#define PARTS_ 8

__device__ __forceinline__ float bf_lo(uint32_t w) { return __uint_as_float(w << 16); }
__device__ __forceinline__ float bf_hi(uint32_t w) { return __uint_as_float(w & 0xffff0000u); }

__device__ __forceinline__ float agent_load(const float* p) {
    return __hip_atomic_load(p, __ATOMIC_RELAXED, __HIP_MEMORY_SCOPE_AGENT);
}
__device__ __forceinline__ void agent_store(float* p, float v) {
    __hip_atomic_store(p, v, __ATOMIC_RELAXED, __HIP_MEMORY_SCOPE_AGENT);
}

__global__ __launch_bounds__(256, 4) void routing_kernel(
    const float* __restrict__ u, const float* __restrict__ b_in,
    float* __restrict__ s_part, uint32_t* __restrict__ u16,
    float* __restrict__ out)
{
    cg::grid_group grid = cg::this_grid();
    const int bid  = blockIdx.x, tid = threadIdx.x;
    const int l    = tid & 15, h = l >> 3;
    const int b    = bid / PARTS_;
    const int part = bid % PARTS_;
    const int ich0 = part * UPB_;
    const int wave = tid >> 6, lane = tid & 63;

    __shared__ float red[4][ROW_];
    __shared__ float v_lds[ROW_];

    // ---------------- P0: f32 u -> s_part[0], write bf16 copy ----------------
    {
        float acc = 0.f;
        for (int uu = 0; uu < UPB_; ++uu) {
            const int i = (ich0 + uu) * ICH_ + (tid >> 4);
            const float* up = u + (size_t)(b * IC_ + i) * ROW_;
            float2 uv[5];
#pragma unroll
            for (int k = 0; k < 5; ++k)
                uv[k] = *(const float2*)(up + 32 * k + 2 * l);

            uint32_t* wp = u16 + (size_t)(b * IC_ + i) * WPS_;
#pragma unroll
            for (int k = 0; k < 5; ++k) {
                __hip_bfloat16 bx = __float2bfloat16(uv[k].x);
                __hip_bfloat16 by = __float2bfloat16(uv[k].y);
                uint32_t w = ((uint32_t)(*(const uint16_t*)&by) << 16) |
                              (uint32_t)(*(const uint16_t*)&bx);
                wp[16 * k + l] = w;
            }

            float own[5], oth[5];
#pragma unroll
            for (int k = 0; k < 5; ++k) own[k] = b_in[i * OC_ + 2 * k + h];
            float m = -1e30f;
#pragma unroll
            for (int k = 0; k < 5; ++k) {
                oth[k] = __shfl_xor(own[k], 8, 16);
                m = fmaxf(m, fmaxf(own[k], oth[k]));
            }
            float sum = 0.f;
#pragma unroll
            for (int k = 0; k < 5; ++k) {
                own[k] = __expf(own[k] - m);
                sum += own[k] + __expf(oth[k] - m);
            }
            const float inv = 1.f / sum;

            float2 sc[5];
#pragma unroll
            for (int k = 0; k < 5; ++k) {
                float c = own[k] * inv;
                sc[k].x = c * uv[k].x; sc[k].y = c * uv[k].y;
            }
#pragma unroll
            for (int k = 0; k < 5; ++k) {
                sc[k].x += __shfl_xor(sc[k].x, 16); sc[k].y += __shfl_xor(sc[k].y, 16);
                sc[k].x += __shfl_xor(sc[k].x, 32); sc[k].y += __shfl_xor(sc[k].y, 32);
            }
            if (lane < 16) {
#pragma unroll
                for (int k = 0; k < 5; ++k)
                    *(float2*)&red[wave][32 * k + 2 * l] = sc[k];
            }
            __syncthreads();
            if (tid < ROW_)
                acc += red[0][tid] + red[1][tid] + red[2][tid] + red[3][tid];
            __syncthreads();
        }
        if (tid < ROW_)
            agent_store(&s_part[((0 * B_ + b) * PARTS_ + part) * ROW_ + tid], acc);
    }
    __threadfence();
    grid.sync();

    // ---------------- P1..P3: bf16 u; v_lds = sum of squash(s_t), t<T -------
    for (int T = 1; T <= 3; ++T) {
        if (tid < ROW_) {
            float vsum = 0.f;
            for (int t = 0; t < T; ++t) {
                float x = 0.f;
#pragma unroll
                for (int p = 0; p < PARTS_; ++p)
                    x += agent_load(&s_part[((t * B_ + b) * PARTS_ + p) * ROW_ + tid]);
                float sq = x * x;
                sq += __shfl_xor(sq, 1, 16);
                sq += __shfl_xor(sq, 2, 16);
                sq += __shfl_xor(sq, 4, 16);
                sq += __shfl_xor(sq, 8, 16);
                vsum += (sq / (1.f + sq)) * x * rsqrtf(sq + 1e-8f);
            }
            v_lds[tid] = vsum;
        }
        __syncthreads();

        float acc = 0.f;
        for (int uu = 0; uu < UPB_; ++uu) {
            const int i = (ich0 + uu) * ICH_ + (tid >> 4);
            const uint32_t* wp = u16 + (size_t)(b * IC_ + i) * WPS_;
            uint32_t uw[5];
#pragma unroll
            for (int k = 0; k < 5; ++k) uw[k] = wp[16 * k + l];

            float own[5], oth[5];
#pragma unroll
            for (int k = 0; k < 5; ++k) {
                float2 vv = *(const float2*)&v_lds[32 * k + 2 * l];
                float pd = bf_lo(uw[k]) * vv.x + bf_hi(uw[k]) * vv.y;
                pd += __shfl_xor(pd, 1, 16);
                pd += __shfl_xor(pd, 2, 16);
                pd += __shfl_xor(pd, 4, 16);
                own[k] = b_in[i * OC_ + 2 * k + h] + pd;
            }
            float m = -1e30f;
#pragma unroll
            for (int k = 0; k < 5; ++k) {
                oth[k] = __shfl_xor(own[k], 8, 16);
                m = fmaxf(m, fmaxf(own[k], oth[k]));
            }
            float sum = 0.f;
#pragma unroll
            for (int k = 0; k < 5; ++k) {
                own[k] = __expf(own[k] - m);
                sum += own[k] + __expf(oth[k] - m);
            }
            const float inv = 1.f / sum;

            float2 sc[5];
#pragma unroll
            for (int k = 0; k < 5; ++k) {
                float c = own[k] * inv;
                sc[k].x = c * bf_lo(uw[k]); sc[k].y = c * bf_hi(uw[k]);
            }
#pragma unroll
            for (int k = 0; k < 5; ++k) {
                sc[k].x += __shfl_xor(sc[k].x, 16); sc[k].y += __shfl_xor(sc[k].y, 16);
                sc[k].x += __shfl_xor(sc[k].x, 32); sc[k].y += __shfl_xor(sc[k].y, 32);
            }
            if (lane < 16) {
#pragma unroll
                for (int k = 0; k < 5; ++k)
                    *(float2*)&red[wave][32 * k + 2 * l] = sc[k];
            }
            __syncthreads();
            if (tid < ROW_)
                acc += red[0][tid] + red[1][tid] + red[2][tid] + red[3][tid];
            __syncthreads();
        }
        if (tid < ROW_)
            agent_store(&s_part[((T * B_ + b) * PARTS_ + part) * ROW_ + tid], acc);
        __threadfence();
        grid.sync();
    }

    // ---------------- F: squash s3 -> out ----------------
    {
        const int idx = bid * 256 + tid;
        if (idx < SOUT_) {
            const int b2 = idx / ROW_, r = idx % ROW_;
            float x = 0.f;
#pragma unroll
            for (int p = 0; p < PARTS_; ++p)
                x += agent_load(&s_part[((3 * B_ + b2) * PARTS_ + p) * ROW_ + r]);
            float sq = x * x;
            sq += __shfl_xor(sq, 1, 16);
            sq += __shfl_xor(sq, 2, 16);
            sq += __shfl_xor(sq, 4, 16);
            sq += __shfl_xor(sq, 8, 16);
            out[idx] = (sq / (1.f + sq)) * x * rsqrtf(sq + 1e-8f);
        }
    }
}

extern "C" void kernel_launch(void* const* d_in, const int* in_sizes, int n_in,
                              void* d_out, int out_size, void* d_ws, size_t ws_size,
                              hipStream_t stream) {
    const float* u    = (const float*)d_in[0];
    const float* b_in = (const float*)d_in[1];
    float* out = (float*)d_out;

    float*    s_part = (float*)d_ws;                       // 4*128*8*160 f32 = 2.62 MB
    uint32_t* u16    = (uint32_t*)(s_part + 4 * B_ * PARTS_ * ROW_); // 47.2 MB

    void* args[] = { (void*)&u, (void*)&b_in, (void*)&s_part, (void*)&u16, (void*)&out };
    hipLaunchCooperativeKernel((const void*)routing_kernel,
                               dim3(NBLK_), dim3(256), args, 0, stream);
}

// Round 5
// 92.325 us; speedup vs baseline: 10.3721x; 10.3721x over previous
//
#include <hip/hip_runtime.h>
#include <hip/hip_bf16.h>

// AgreementRouting, 2-kernel plan. B=128, IC=1152, OC=10, D=16, 3 iters, f32.
//
// A (1024 blk x 256 thr): read f32 u ONCE -> bf16 copy u16 + per-block s0
//    partials (plain stores, no atomics, no pre-zero).
// B (128 blk x 1024 thr, one block per b): sum partials -> v1; 3 phases, each
//    streams u16[b] (368KB, L3-resident) with block-local LDS reduction and
//    in-LDS squash. Logits: bb_T = b_in + <u, sum_{t<T} v_t> (linearity).
//    No inter-block sync anywhere -> no cooperative launch, no deadlock risk.
//
// Lane scheme per 16-lane group (slice = 10x16 f32): l=tid&15, h=l>>3.
// Lane owns (j=2k+h, d=2(l&7)..2(l&7)+1), k=0..4 == float offset 32k+2l.

#define B_    128
#define IC_   1152
#define OC_   10
#define ROW_  160
#define WPS_  80          // bf16 dwords per slice
#define APARTS 8
#define ASPB   144        // slices per A-part
#define AUPB   9          // slices per 16-lane group in A
#define BGRP   64         // 16-lane groups in B (1024 thr)
#define BUPB   18         // slices per group in B (1152/64)
#define BNW    16         // waves in B

__device__ __forceinline__ float bf_lo(uint32_t w) { return __uint_as_float(w << 16); }
__device__ __forceinline__ float bf_hi(uint32_t w) { return __uint_as_float(w & 0xffff0000u); }

// ---------------- Kernel A ----------------
__global__ __launch_bounds__(256) void a_kernel(
    const float* __restrict__ u, const float* __restrict__ b_in,
    uint32_t* __restrict__ u16, float* __restrict__ s_part)
{
    const int bid = blockIdx.x, tid = threadIdx.x;
    const int l = tid & 15, h = l >> 3, g = tid >> 4;
    const int b = bid >> 3, part = bid & 7;
    const int wave = tid >> 6, lane = tid & 63;
    __shared__ float red[4][ROW_];

    float2 sc[5];
#pragma unroll
    for (int k = 0; k < 5; ++k) { sc[k].x = 0.f; sc[k].y = 0.f; }

    for (int uu = 0; uu < AUPB; ++uu) {
        const int i = part * ASPB + uu * 16 + g;
        const float* up = u + (size_t)(b * IC_ + i) * ROW_;
        float2 uv[5];
#pragma unroll
        for (int k = 0; k < 5; ++k)
            uv[k] = *(const float2*)(up + 32 * k + 2 * l);

        uint32_t* wp = u16 + (size_t)(b * IC_ + i) * WPS_;
#pragma unroll
        for (int k = 0; k < 5; ++k) {
            __hip_bfloat16 bx = __float2bfloat16(uv[k].x);
            __hip_bfloat16 by = __float2bfloat16(uv[k].y);
            wp[16 * k + l] = ((uint32_t)(*(const uint16_t*)&by) << 16) |
                              (uint32_t)(*(const uint16_t*)&bx);
        }

        float own[5], oth[5];
#pragma unroll
        for (int k = 0; k < 5; ++k) own[k] = b_in[i * OC_ + 2 * k + h];
        float m = -1e30f;
#pragma unroll
        for (int k = 0; k < 5; ++k) {
            oth[k] = __shfl_xor(own[k], 8, 16);
            m = fmaxf(m, fmaxf(own[k], oth[k]));
        }
        float sum = 0.f;
#pragma unroll
        for (int k = 0; k < 5; ++k) {
            own[k] = __expf(own[k] - m);
            sum += own[k] + __expf(oth[k] - m);
        }
        const float inv = 1.f / sum;
#pragma unroll
        for (int k = 0; k < 5; ++k) {
            float c = own[k] * inv;
            sc[k].x += c * uv[k].x; sc[k].y += c * uv[k].y;
        }
    }

#pragma unroll
    for (int k = 0; k < 5; ++k) {
        sc[k].x += __shfl_xor(sc[k].x, 16); sc[k].y += __shfl_xor(sc[k].y, 16);
        sc[k].x += __shfl_xor(sc[k].x, 32); sc[k].y += __shfl_xor(sc[k].y, 32);
    }
    if (lane < 16) {
#pragma unroll
        for (int k = 0; k < 5; ++k)
            *(float2*)&red[wave][32 * k + 2 * l] = sc[k];
    }
    __syncthreads();
    if (tid < ROW_) {
        float t = red[0][tid] + red[1][tid] + red[2][tid] + red[3][tid];
        s_part[(size_t)(b * APARTS + part) * ROW_ + tid] = t;
    }
}

// ---------------- Kernel B ----------------
__global__ __launch_bounds__(1024) void b_kernel(
    const uint32_t* __restrict__ u16, const float* __restrict__ b_in,
    const float* __restrict__ s_part, float* __restrict__ out)
{
    const int b = blockIdx.x, tid = threadIdx.x;
    const int l = tid & 15, h = l >> 3, g = tid >> 4;
    const int wave = tid >> 6, lane = tid & 63;

    __shared__ float red[BNW][ROW_];
    __shared__ float v_lds[ROW_];

    float vsum = 0.f;    // valid for tid<ROW_
    // s0 from partials -> v1
    if (tid < ROW_) {
        const float* sp = s_part + (size_t)b * APARTS * ROW_;
        float x = 0.f;
#pragma unroll
        for (int p = 0; p < APARTS; ++p) x += sp[p * ROW_ + tid];
        float sq = x * x;
        sq += __shfl_xor(sq, 1, 16);
        sq += __shfl_xor(sq, 2, 16);
        sq += __shfl_xor(sq, 4, 16);
        sq += __shfl_xor(sq, 8, 16);
        vsum = (sq / (1.f + sq)) * x * rsqrtf(sq + 1e-8f);
        v_lds[tid] = vsum;
    }
    __syncthreads();

    for (int T = 1; T <= 3; ++T) {
        float2 sc[5];
#pragma unroll
        for (int k = 0; k < 5; ++k) { sc[k].x = 0.f; sc[k].y = 0.f; }

        for (int uu = 0; uu < BUPB; ++uu) {
            const int i = uu * BGRP + g;
            const uint32_t* wp = u16 + (size_t)(b * IC_ + i) * WPS_;
            uint32_t uw[5];
#pragma unroll
            for (int k = 0; k < 5; ++k) uw[k] = wp[16 * k + l];

            float own[5], oth[5];
#pragma unroll
            for (int k = 0; k < 5; ++k) {
                float2 vv = *(const float2*)&v_lds[32 * k + 2 * l];
                float pd = bf_lo(uw[k]) * vv.x + bf_hi(uw[k]) * vv.y;
                pd += __shfl_xor(pd, 1, 16);
                pd += __shfl_xor(pd, 2, 16);
                pd += __shfl_xor(pd, 4, 16);
                own[k] = b_in[i * OC_ + 2 * k + h] + pd;
            }
            float m = -1e30f;
#pragma unroll
            for (int k = 0; k < 5; ++k) {
                oth[k] = __shfl_xor(own[k], 8, 16);
                m = fmaxf(m, fmaxf(own[k], oth[k]));
            }
            float sum = 0.f;
#pragma unroll
            for (int k = 0; k < 5; ++k) {
                own[k] = __expf(own[k] - m);
                sum += own[k] + __expf(oth[k] - m);
            }
            const float inv = 1.f / sum;
#pragma unroll
            for (int k = 0; k < 5; ++k) {
                float c = own[k] * inv;
                sc[k].x += c * bf_lo(uw[k]); sc[k].y += c * bf_hi(uw[k]);
            }
        }

#pragma unroll
        for (int k = 0; k < 5; ++k) {
            sc[k].x += __shfl_xor(sc[k].x, 16); sc[k].y += __shfl_xor(sc[k].y, 16);
            sc[k].x += __shfl_xor(sc[k].x, 32); sc[k].y += __shfl_xor(sc[k].y, 32);
        }
        if (lane < 16) {
#pragma unroll
            for (int k = 0; k < 5; ++k)
                *(float2*)&red[wave][32 * k + 2 * l] = sc[k];
        }
        __syncthreads();
        if (tid < ROW_) {
            float x = 0.f;
#pragma unroll
            for (int w = 0; w < BNW; ++w) x += red[w][tid];
            float sq = x * x;
            sq += __shfl_xor(sq, 1, 16);
            sq += __shfl_xor(sq, 2, 16);
            sq += __shfl_xor(sq, 4, 16);
            sq += __shfl_xor(sq, 8, 16);
            float v = (sq / (1.f + sq)) * x * rsqrtf(sq + 1e-8f);
            if (T < 3) {
                vsum += v;
                v_lds[tid] = vsum;
            } else {
                out[b * ROW_ + tid] = v;
            }
        }
        __syncthreads();   // red reuse + v_lds visibility for next phase
    }
}

extern "C" void kernel_launch(void* const* d_in, const int* in_sizes, int n_in,
                              void* d_out, int out_size, void* d_ws, size_t ws_size,
                              hipStream_t stream) {
    const float* u    = (const float*)d_in[0];
    const float* b_in = (const float*)d_in[1];
    float* out = (float*)d_out;

    float*    s_part = (float*)d_ws;                          // 128*8*160 f32 = 655 KB
    uint32_t* u16    = (uint32_t*)(s_part + B_ * APARTS * ROW_); // 47.2 MB

    a_kernel<<<dim3(B_ * APARTS), dim3(256), 0, stream>>>(u, b_in, u16, s_part);
    b_kernel<<<dim3(B_), dim3(1024), 0, stream>>>(u16, b_in, s_part, out);
}

// Round 6
// 74.178 us; speedup vs baseline: 12.9096x; 1.2447x over previous
//
#include <hip/hip_runtime.h>
#include <hip/hip_bf16.h>

// AgreementRouting, 2-kernel plan + DPP cross-lane (no DS-pipe in hot loop).
// B=128, IC=1152, OC=10, D=16, 3 iters, f32 in/out.
//
// A (1024 blk x 256 thr): read f32 u ONCE -> bf16 copy u16 + per-block s0
//    partials (plain stores, no atomics, no pre-zero).
// B (128 blk x 1024 thr, one block per b): sum partials -> v1; 3 phases, each
//    streams u16[b] (368KB) with block-local LDS reduction and in-LDS squash.
//    Logits: bb_T = b_in + <u, sum_{t<T} v_t> (linearity).
//
// Hot-loop cross-lane is ALL DPP (VALU pipe): xor1=quad_perm(0xB1),
// xor2=quad_perm(0x4E), "xor4" within 8 = row_half_mirror(0x141) (valid after
// the xor1/xor2 butterfly: every lane of a quad holds the quad sum),
// xor8 within 16 = row_ror:8(0x128) (exactly equals xor8).
// exp count halved: lane exponentiates only its own 5 logits; max/denom
// exchanged across the h-halves with one DPP max / one DPP add.
//
// Lane scheme per 16-lane group (slice = 10x16 f32): l=tid&15, h=l>>3.
// Lane owns (j=2k+h, d=2(l&7)..2(l&7)+1), k=0..4 == float offset 32k+2l.

#define B_    128
#define IC_   1152
#define OC_   10
#define ROW_  160
#define WPS_  80          // bf16 dwords per slice
#define APARTS 8
#define ASPB   144        // slices per A-part
#define AUPB   9          // slices per 16-lane group in A
#define BGRP   64         // 16-lane groups in B (1024 thr)
#define BUPB   18         // slices per group in B (1152/64)
#define BNW    16         // waves in B

__device__ __forceinline__ float bf_lo(uint32_t w) { return __uint_as_float(w << 16); }
__device__ __forceinline__ float bf_hi(uint32_t w) { return __uint_as_float(w & 0xffff0000u); }

template<int CTRL>
__device__ __forceinline__ float dppf(float x) {
    return __int_as_float(__builtin_amdgcn_update_dpp(
        0, __float_as_int(x), CTRL, 0xF, 0xF, true));
}
// sum over the 8 lanes sharing h (lane bits 0..2), replicated
__device__ __forceinline__ float dpp_sum8(float x) {
    x += dppf<0xB1>(x);    // quad_perm [1,0,3,2]  (xor1)
    x += dppf<0x4E>(x);    // quad_perm [2,3,0,1]  (xor2)
    x += dppf<0x141>(x);   // row_half_mirror      (cross-quad within 8)
    return x;
}

// softmax over 10 logits own[5] (lane h owns j=2k+h); returns inv-denominator,
// own[] replaced by exp(own - max). One DPP max + one DPP add across halves.
__device__ __forceinline__ float softmax10(float own[5]) {
    float m = own[0];
#pragma unroll
    for (int k = 1; k < 5; ++k) m = fmaxf(m, own[k]);
    m = fmaxf(m, dppf<0x128>(m));          // row_ror:8 == xor8
    float sum = 0.f;
#pragma unroll
    for (int k = 0; k < 5; ++k) { own[k] = __expf(own[k] - m); sum += own[k]; }
    sum += dppf<0x128>(sum);
    return 1.f / sum;
}

// ---------------- Kernel A ----------------
__global__ __launch_bounds__(256) void a_kernel(
    const float* __restrict__ u, const float* __restrict__ b_in,
    uint32_t* __restrict__ u16, float* __restrict__ s_part)
{
    const int bid = blockIdx.x, tid = threadIdx.x;
    const int l = tid & 15, h = l >> 3, g = tid >> 4;
    const int b = bid >> 3, part = bid & 7;
    const int wave = tid >> 6, lane = tid & 63;
    __shared__ float red[4][ROW_];

    float2 sc[5];
#pragma unroll
    for (int k = 0; k < 5; ++k) { sc[k].x = 0.f; sc[k].y = 0.f; }

    for (int uu = 0; uu < AUPB; ++uu) {
        const int i = part * ASPB + uu * 16 + g;
        const float* up = u + (size_t)(b * IC_ + i) * ROW_;
        float2 uv[5];
#pragma unroll
        for (int k = 0; k < 5; ++k)
            uv[k] = *(const float2*)(up + 32 * k + 2 * l);

        uint32_t* wp = u16 + (size_t)(b * IC_ + i) * WPS_;
#pragma unroll
        for (int k = 0; k < 5; ++k) {
            __hip_bfloat16 bx = __float2bfloat16(uv[k].x);
            __hip_bfloat16 by = __float2bfloat16(uv[k].y);
            wp[16 * k + l] = ((uint32_t)(*(const uint16_t*)&by) << 16) |
                              (uint32_t)(*(const uint16_t*)&bx);
        }

        float own[5];
#pragma unroll
        for (int k = 0; k < 5; ++k) own[k] = b_in[i * OC_ + 2 * k + h];
        const float inv = softmax10(own);
#pragma unroll
        for (int k = 0; k < 5; ++k) {
            float c = own[k] * inv;
            sc[k].x += c * uv[k].x; sc[k].y += c * uv[k].y;
        }
    }

#pragma unroll
    for (int k = 0; k < 5; ++k) {
        sc[k].x += __shfl_xor(sc[k].x, 16); sc[k].y += __shfl_xor(sc[k].y, 16);
        sc[k].x += __shfl_xor(sc[k].x, 32); sc[k].y += __shfl_xor(sc[k].y, 32);
    }
    if (lane < 16) {
#pragma unroll
        for (int k = 0; k < 5; ++k)
            *(float2*)&red[wave][32 * k + 2 * l] = sc[k];
    }
    __syncthreads();
    if (tid < ROW_) {
        float t = red[0][tid] + red[1][tid] + red[2][tid] + red[3][tid];
        s_part[(size_t)(b * APARTS + part) * ROW_ + tid] = t;
    }
}

// ---------------- Kernel B ----------------
__global__ __launch_bounds__(1024) void b_kernel(
    const uint32_t* __restrict__ u16, const float* __restrict__ b_in,
    const float* __restrict__ s_part, float* __restrict__ out)
{
    const int b = blockIdx.x, tid = threadIdx.x;
    const int l = tid & 15, h = l >> 3, g = tid >> 4;
    const int wave = tid >> 6, lane = tid & 63;

    __shared__ float red[BNW][ROW_];
    __shared__ float v_lds[ROW_];

    float vsum = 0.f;    // valid for tid<ROW_
    if (tid < ROW_) {
        const float* sp = s_part + (size_t)b * APARTS * ROW_;
        float x = 0.f;
#pragma unroll
        for (int p = 0; p < APARTS; ++p) x += sp[p * ROW_ + tid];
        float sq = x * x;
        sq += __shfl_xor(sq, 1, 16);
        sq += __shfl_xor(sq, 2, 16);
        sq += __shfl_xor(sq, 4, 16);
        sq += __shfl_xor(sq, 8, 16);
        vsum = (sq / (1.f + sq)) * x * rsqrtf(sq + 1e-8f);
        v_lds[tid] = vsum;
    }
    __syncthreads();

    for (int T = 1; T <= 3; ++T) {
        // hoist v into registers: slice-invariant within a phase
        float2 vv[5];
#pragma unroll
        for (int k = 0; k < 5; ++k)
            vv[k] = *(const float2*)&v_lds[32 * k + 2 * l];

        float2 sc[5];
#pragma unroll
        for (int k = 0; k < 5; ++k) { sc[k].x = 0.f; sc[k].y = 0.f; }

        for (int uu = 0; uu < BUPB; ++uu) {
            const int i = uu * BGRP + g;
            const uint32_t* wp = u16 + (size_t)(b * IC_ + i) * WPS_;
            uint32_t uw[5];
#pragma unroll
            for (int k = 0; k < 5; ++k) uw[k] = wp[16 * k + l];

            float own[5];
#pragma unroll
            for (int k = 0; k < 5; ++k) {
                float pd = bf_lo(uw[k]) * vv[k].x + bf_hi(uw[k]) * vv[k].y;
                own[k] = b_in[i * OC_ + 2 * k + h] + dpp_sum8(pd);
            }
            const float inv = softmax10(own);
#pragma unroll
            for (int k = 0; k < 5; ++k) {
                float c = own[k] * inv;
                sc[k].x += c * bf_lo(uw[k]); sc[k].y += c * bf_hi(uw[k]);
            }
        }

#pragma unroll
        for (int k = 0; k < 5; ++k) {
            sc[k].x += __shfl_xor(sc[k].x, 16); sc[k].y += __shfl_xor(sc[k].y, 16);
            sc[k].x += __shfl_xor(sc[k].x, 32); sc[k].y += __shfl_xor(sc[k].y, 32);
        }
        if (lane < 16) {
#pragma unroll
            for (int k = 0; k < 5; ++k)
                *(float2*)&red[wave][32 * k + 2 * l] = sc[k];
        }
        __syncthreads();
        if (tid < ROW_) {
            float x = 0.f;
#pragma unroll
            for (int w = 0; w < BNW; ++w) x += red[w][tid];
            float sq = x * x;
            sq += __shfl_xor(sq, 1, 16);
            sq += __shfl_xor(sq, 2, 16);
            sq += __shfl_xor(sq, 4, 16);
            sq += __shfl_xor(sq, 8, 16);
            float v = (sq / (1.f + sq)) * x * rsqrtf(sq + 1e-8f);
            if (T < 3) {
                vsum += v;
                v_lds[tid] = vsum;
            } else {
                out[b * ROW_ + tid] = v;
            }
        }
        __syncthreads();
    }
}

extern "C" void kernel_launch(void* const* d_in, const int* in_sizes, int n_in,
                              void* d_out, int out_size, void* d_ws, size_t ws_size,
                              hipStream_t stream) {
    const float* u    = (const float*)d_in[0];
    const float* b_in = (const float*)d_in[1];
    float* out = (float*)d_out;

    float*    s_part = (float*)d_ws;                          // 128*8*160 f32
    uint32_t* u16    = (uint32_t*)(s_part + B_ * APARTS * ROW_); // 47.2 MB

    a_kernel<<<dim3(B_ * APARTS), dim3(256), 0, stream>>>(u, b_in, u16, s_part);
    b_kernel<<<dim3(B_), dim3(1024), 0, stream>>>(u16, b_in, s_part, out);
}